// Round 2
// baseline (180.395 us; speedup 1.0000x reference)
//
#include <hip/hip_runtime.h>

// TripletColbertLoss on MFMA: q (B,Q,D), p/n (B,K,D) fp32 -> scalar.
// loss = relu(0.2 + neg - pos), score = sum_{b,q} max_k q.d
// B=256 Q=256 K=512 D=128.
//
// R4 (resubmit — R1 bench was a container infra failure, kernel never ran):
// occupancy re-block. R3 held 64 q-rows/wave -> ~224 unified VGPR+AGPR/lane
// -> 2 waves/SIMD; MfmaUtil 29% with MFMA floor ~35% of runtime = pipe
// starved by latency, not work. Now 512-thr blocks, 8 waves x 32 q-rows,
// per-wave A-frags halved (64 regs) -> total ~120 regs,
// __launch_bounds__(512,4) -> 4 waves/SIMD, 16 waves/CU. Same 16x16x32 MFMA,
// same bf16 truncation 3-term split, same LDS tile layout (verified).

#define MARGIN   0.2f
#define Bn       256
#define Qn       256
#define Kn       512
#define Dn       128
#define TN       32            // docs per tile
#define NT       (Kn / TN)     // 16 tiles
#define BSTR     136           // doc stride (bf16 units): 272 B, 16B-aligned
#define NTHREADS 512

typedef __attribute__((ext_vector_type(8))) short short8;
typedef __attribute__((ext_vector_type(4))) short short4v;
typedef __attribute__((ext_vector_type(4))) float f32x4;

// Truncation split: x = hi + lo (both bf16 by bit-truncation). hi err <= 2^-8
// is captured exactly by lo; lo trunc err ~2^-17 of x. Cheap: shifts only.
__device__ __forceinline__ void split_trunc(float x, unsigned short& hi, unsigned short& lo) {
    unsigned int u = __float_as_uint(x);
    hi = (unsigned short)(u >> 16);
    float l = x - __uint_as_float(u & 0xFFFF0000u);
    lo = (unsigned short)(__float_as_uint(l) >> 16);
}

__global__ __launch_bounds__(NTHREADS, 4)
void colbert_pass_kernel(const float* __restrict__ qg,
                         const float* __restrict__ pg,
                         const float* __restrict__ ng,
                         double* __restrict__ sum_ws) {
    __shared__ short Bs[2][2][TN * BSTR];   // [buf][hi/lo][doc*BSTR + dim]  34816 B
    __shared__ float part[8];

    const int tid  = threadIdx.x;
    const int w    = tid >> 6;              // 8 waves
    const int lane = tid & 63;
    const int l16  = lane & 15;
    const int quad = lane >> 4;
    const int b    = blockIdx.x;
    const int pass = blockIdx.y;            // 0 -> p (+), 1 -> n (-)

    const float* docb = (pass ? ng : pg) + (size_t)b * Kn * Dn;

    // Prefetch tile 0 first: get global loads in flight before A-conversion VALU.
    float4 pre[2];
    {
        const float4* s4 = (const float4*)docb;
#pragma unroll
        for (int k = 0; k < 2; ++k) pre[k] = s4[tid + 512 * k];
    }

    // ---- A fragments: 32 q-rows per wave (mi = 0,1 -> 16 rows each).
    // 16x16x32 A layout: lane holds A[m = l16][k = quad*8 + j], j=0..7.
    short8 Ahi[2][4], Alo[2][4];            // [mi][ks]  -> 64 VGPRs
    {
        const float* qb = qg + (size_t)b * Qn * Dn;
#pragma unroll
        for (int mi = 0; mi < 2; ++mi)
#pragma unroll
            for (int ks = 0; ks < 4; ++ks) {
                const float* src = qb + (size_t)(w * 32 + mi * 16 + l16) * Dn
                                      + ks * 32 + quad * 8;
                float4 v0 = *(const float4*)src;
                float4 v1 = *(const float4*)(src + 4);
                float x[8] = {v0.x, v0.y, v0.z, v0.w, v1.x, v1.y, v1.z, v1.w};
#pragma unroll
                for (int j = 0; j < 8; ++j) {
                    unsigned short h, l;
                    split_trunc(x[j], h, l);
                    Ahi[mi][ks][j] = (short)h;
                    Alo[mi][ks][j] = (short)l;
                }
            }
    }

    float maxv[2][4];                       // [mi][reg] running row-max
#pragma unroll
    for (int mi = 0; mi < 2; ++mi)
#pragma unroll
        for (int r = 0; r < 4; ++r) maxv[mi][r] = -3e38f;

    int buf = 0;
    for (int t = 0; t < NT; ++t) {
        // convert tile t -> LDS[buf] (hi & lo planes). 512 thr x 8 floats.
#pragma unroll
        for (int k = 0; k < 2; ++k) {
            int i   = tid + 512 * k;
            int doc = i >> 5;              // 32 float4 per doc
            int d4  = i & 31;
            float4 v = pre[k];
            float x[4] = {v.x, v.y, v.z, v.w};
            short4v hi, lo;
#pragma unroll
            for (int j = 0; j < 4; ++j) {
                unsigned short h, l;
                split_trunc(x[j], h, l);
                hi[j] = (short)h;
                lo[j] = (short)l;
            }
            *(short4v*)&Bs[buf][0][doc * BSTR + d4 * 4] = hi;
            *(short4v*)&Bs[buf][1][doc * BSTR + d4 * 4] = lo;
        }
        __syncthreads();

        // prefetch tile t+1 while MFMAs run
        if (t + 1 < NT) {
            const float4* s4 = (const float4*)(docb + (size_t)(t + 1) * TN * Dn);
#pragma unroll
            for (int k = 0; k < 2; ++k) pre[k] = s4[tid + 512 * k];
        }

        f32x4 acc[2][2];                    // [mi][ni]
#pragma unroll
        for (int mi = 0; mi < 2; ++mi)
#pragma unroll
            for (int ni = 0; ni < 2; ++ni) acc[mi][ni] = (f32x4){0.f, 0.f, 0.f, 0.f};

#pragma unroll
        for (int ni = 0; ni < 2; ++ni) {
#pragma unroll
            for (int ks = 0; ks < 4; ++ks) {
                int off = (ni * 16 + l16) * BSTR + ks * 32 + quad * 8;
                short8 bh = *(const short8*)&Bs[buf][0][off];
                short8 bl = *(const short8*)&Bs[buf][1][off];
                // 2 interleaved acc chains per ni; 3 split-terms per ks.
                acc[0][ni] = __builtin_amdgcn_mfma_f32_16x16x32_bf16(
                    Ahi[0][ks], bh, acc[0][ni], 0, 0, 0);
                acc[1][ni] = __builtin_amdgcn_mfma_f32_16x16x32_bf16(
                    Ahi[1][ks], bh, acc[1][ni], 0, 0, 0);
                acc[0][ni] = __builtin_amdgcn_mfma_f32_16x16x32_bf16(
                    Alo[0][ks], bh, acc[0][ni], 0, 0, 0);
                acc[1][ni] = __builtin_amdgcn_mfma_f32_16x16x32_bf16(
                    Alo[1][ks], bh, acc[1][ni], 0, 0, 0);
                acc[0][ni] = __builtin_amdgcn_mfma_f32_16x16x32_bf16(
                    Ahi[0][ks], bl, acc[0][ni], 0, 0, 0);
                acc[1][ni] = __builtin_amdgcn_mfma_f32_16x16x32_bf16(
                    Ahi[1][ks], bl, acc[1][ni], 0, 0, 0);
            }
        }

        // C/D layout: col(doc)=l16, row=quad*4+reg
#pragma unroll
        for (int mi = 0; mi < 2; ++mi)
#pragma unroll
            for (int r = 0; r < 4; ++r)
                maxv[mi][r] = fmaxf(maxv[mi][r], fmaxf(acc[mi][0][r], acc[mi][1][r]));
        buf ^= 1;
    }

    // max over the 16 doc-column lanes
#pragma unroll
    for (int off = 1; off < 16; off <<= 1)
#pragma unroll
        for (int mi = 0; mi < 2; ++mi)
#pragma unroll
            for (int r = 0; r < 4; ++r)
                maxv[mi][r] = fmaxf(maxv[mi][r], __shfl_xor(maxv[mi][r], off));

    float s = 0.f;
#pragma unroll
    for (int mi = 0; mi < 2; ++mi)
#pragma unroll
        for (int r = 0; r < 4; ++r) s += maxv[mi][r];
    if (l16 != 0) s = 0.f;                  // one copy per quad
    s += __shfl_xor(s, 16);                 // combine the 4 quads
    s += __shfl_xor(s, 32);
    if (lane == 0) part[w] = s;
    __syncthreads();
    if (tid == 0) {
        double t = 0.0;
#pragma unroll
        for (int i = 0; i < 8; ++i) t += (double)part[i];
        atomicAdd(sum_ws, pass ? -t : t);   // S = pos - neg, exact in fp64
    }
}

__global__ void finalize_kernel(const double* __restrict__ sum_ws,
                                float* __restrict__ out) {
    out[0] = fmaxf(0.0f, MARGIN - (float)sum_ws[0]);
}

extern "C" void kernel_launch(void* const* d_in, const int* in_sizes, int n_in,
                              void* d_out, int out_size, void* d_ws, size_t ws_size,
                              hipStream_t stream) {
    const float* q = (const float*)d_in[0];
    const float* p = (const float*)d_in[1];
    const float* n = (const float*)d_in[2];
    float* out = (float*)d_out;
    double* ws = (double*)d_ws;

    hipMemsetAsync(ws, 0, sizeof(double), stream);  // ws re-poisoned each call

    colbert_pass_kernel<<<dim3(Bn, 2), NTHREADS, 0, stream>>>(q, p, n, ws);
    finalize_kernel<<<1, 1, 0, stream>>>(ws, out);
}